// Round 2
// baseline (711.361 us; speedup 1.0000x reference)
//
#include <hip/hip_runtime.h>
#include <math.h>

#define EPSF 1e-8f

constexpr int D_    = 128;
constexpr int NTOK  = 131072;   // 1024 * 128
constexpr int NLVL  = 4;
constexpr int NCODE = 256;
constexpr int TPB   = 256;
constexpr int TOKB  = 64;       // tokens per block
constexpr int STR   = 132;      // LDS row stride (floats): 16B-aligned rows, 2-way-max bank aliasing

// --- Kernel 1: normalize codebook rows: e_n = e / (||e|| + eps) -------------
__global__ __launch_bounds__(64) void normalize_cb(const float* __restrict__ cb,
                                                   float* __restrict__ out) {
  int row = blockIdx.x;           // 0..1023  (level*256 + code)
  int t   = threadIdx.x;          // 0..63
  float a = cb[row * D_ + t];
  float b = cb[row * D_ + t + 64];
  float ss = a * a + b * b;
#pragma unroll
  for (int m = 32; m >= 1; m >>= 1) ss += __shfl_xor(ss, m);
  float denom = sqrtf(ss) + EPSF;
  out[row * D_ + t]      = a / denom;
  out[row * D_ + t + 64] = b / denom;
}

// --- Kernel 2: main RVQ ------------------------------------------------------
// block = 256 threads (4 waves), 64 tokens. Thread (tg = t>>4, kg = t&15)
// owns tokens tg*4..tg*4+3 and, per 64-code chunk, codes j*16+kg (j=0..3).
__global__ __launch_bounds__(TPB) void rvq_main(const float* __restrict__ x,
                                                const float* __restrict__ en,
                                                float* __restrict__ out_xq,
                                                float* __restrict__ out_idx,
                                                float* __restrict__ out_s,
                                                double* __restrict__ lossacc_g) {
  __shared__ float r_lds[TOKB * STR];   // residual tile  [64][132]
  __shared__ float e_lds[64 * STR];     // codebook chunk [64][132]
  __shared__ float red[4];

  const int t  = threadIdx.x;
  const int kg = t & 15;
  const int tg = t >> 4;
  const size_t n0 = (size_t)blockIdx.x * TOKB;

  // ---- load x tile into residual LDS (coalesced float4) ----
  const float4* __restrict__ x4 = (const float4*)(x + n0 * D_);
#pragma unroll
  for (int g = t; g < TOKB * D_ / 4; g += TPB) {
    float4 v = x4[g];
    *(float4*)&r_lds[(g >> 5) * STR + ((g & 31) << 2)] = v;
  }

  for (int lvl = 0; lvl < NLVL; ++lvl) {
    float best[4];
    int   bidx[4];
#pragma unroll
    for (int i = 0; i < 4; ++i) { best[i] = -3e38f; bidx[i] = 1 << 30; }

    // ---- similarity + running argmax over 4 chunks of 64 codes ----
    for (int c = 0; c < 4; ++c) {
      __syncthreads();  // protects e_lds reuse AND r-updates from prev level
      const float4* __restrict__ eg =
          (const float4*)(en + (size_t)(lvl * NCODE + c * 64) * D_);
#pragma unroll
      for (int g = t; g < 64 * D_ / 4; g += TPB) {
        float4 v = eg[g];
        *(float4*)&e_lds[(g >> 5) * STR + ((g & 31) << 2)] = v;
      }
      __syncthreads();

      float sim[4][4];
#pragma unroll
      for (int i = 0; i < 4; ++i)
#pragma unroll
        for (int j = 0; j < 4; ++j) sim[i][j] = 0.f;

      const float* rb = &r_lds[(tg * 4) * STR];
      const float* eb = &e_lds[kg * STR];
#pragma unroll 4
      for (int d = 0; d < D_; d += 4) {
        float4 rv[4];
#pragma unroll
        for (int i = 0; i < 4; ++i) rv[i] = *(const float4*)&rb[i * STR + d];
#pragma unroll
        for (int j = 0; j < 4; ++j) {
          float4 ev = *(const float4*)&eb[(j * 16) * STR + d];
#pragma unroll
          for (int i = 0; i < 4; ++i) {
            sim[i][j] += rv[i].x * ev.x;
            sim[i][j] += rv[i].y * ev.y;
            sim[i][j] += rv[i].z * ev.z;
            sim[i][j] += rv[i].w * ev.w;
          }
        }
      }

      // merge into running argmax (first-occurrence tie-break, like jnp.argmax)
#pragma unroll
      for (int j = 0; j < 4; ++j) {
        int code = c * 64 + j * 16 + kg;
#pragma unroll
        for (int i = 0; i < 4; ++i) {
          float sv = sim[i][j];
          if (sv > best[i] || (sv == best[i] && code < bidx[i])) {
            best[i] = sv; bidx[i] = code;
          }
        }
      }
    }

    // ---- argmax reduce across the 16 kg lanes (within-wave shuffles) ----
#pragma unroll
    for (int m = 8; m >= 1; m >>= 1) {
#pragma unroll
      for (int i = 0; i < 4; ++i) {
        float ob = __shfl_xor(best[i], m);
        int   oi = __shfl_xor(bidx[i], m);
        if (ob > best[i] || (ob == best[i] && oi < bidx[i])) {
          best[i] = ob; bidx[i] = oi;
        }
      }
    }

    // ---- projection scalar, residual update, loss ----
    float lacc = 0.f;
#pragma unroll
    for (int i = 0; i < 4; ++i) {
      int row = tg * 4 + i;
      int idx = bidx[i];
      const float* ev = en + (size_t)(lvl * NCODE + idx) * D_ + kg * 8;
      float4 ea  = *(const float4*)ev;
      float4 eb2 = *(const float4*)(ev + 4);
      float* rp  = &r_lds[row * STR + kg * 8];
      float4 ra  = *(const float4*)rp;
      float4 rb2 = *(const float4*)(rp + 4);
      float sp = ra.x * ea.x + ra.y * ea.y + ra.z * ea.z + ra.w * ea.w +
                 rb2.x * eb2.x + rb2.y * eb2.y + rb2.z * eb2.z + rb2.w * eb2.w;
#pragma unroll
      for (int m = 8; m >= 1; m >>= 1) sp += __shfl_xor(sp, m);

      float4 na, nb;
      na.x = ra.x - sp * ea.x;   na.y = ra.y - sp * ea.y;
      na.z = ra.z - sp * ea.z;   na.w = ra.w - sp * ea.w;
      nb.x = rb2.x - sp * eb2.x; nb.y = rb2.y - sp * eb2.y;
      nb.z = rb2.z - sp * eb2.z; nb.w = rb2.w - sp * eb2.w;
      *(float4*)rp       = na;
      *(float4*)(rp + 4) = nb;
      lacc += na.x * na.x + na.y * na.y + na.z * na.z + na.w * na.w +
              nb.x * nb.x + nb.y * nb.y + nb.z * nb.z + nb.w * nb.w;

      if (kg == 0) {
        size_t n = n0 + row;
        out_idx[n * 4 + lvl] = (float)idx;
        out_s[n * 4 + lvl]   = sp;
      }
    }

    // ---- block loss reduce -> fp64 atomic per level ----
#pragma unroll
    for (int m = 32; m >= 1; m >>= 1) lacc += __shfl_xor(lacc, m);
    if ((t & 63) == 0) red[t >> 6] = lacc;
    __syncthreads();
    if (t == 0)
      atomicAdd(&lossacc_g[lvl], (double)(red[0] + red[1] + red[2] + red[3]));
  }

  __syncthreads();
  // ---- x_q = x - residual_final ----
  float4* __restrict__ o4 = (float4*)(out_xq + n0 * D_);
#pragma unroll
  for (int g = t; g < TOKB * D_ / 4; g += TPB) {
    float4 xv = x4[g];
    float4 rv = *(const float4*)&r_lds[(g >> 5) * STR + ((g & 31) << 2)];
    float4 o;
    o.x = xv.x - rv.x; o.y = xv.y - rv.y; o.z = xv.z - rv.z; o.w = xv.w - rv.w;
    o4[g] = o;
  }
}

// --- Kernel 3: finalize mean loss -------------------------------------------
// loss_i = (1 + BETA) * sum_i / (N*D);  mean_loss = 0.25 * sum(loss_i)
__global__ void finalize_loss(const double* __restrict__ lossacc_g,
                              float* __restrict__ out_loss) {
  double tot = lossacc_g[0] + lossacc_g[1] + lossacc_g[2] + lossacc_g[3];
  out_loss[0] = (float)(1.25 * tot / (4.0 * 16777216.0));
}

extern "C" void kernel_launch(void* const* d_in, const int* in_sizes, int n_in,
                              void* d_out, int out_size, void* d_ws, size_t ws_size,
                              hipStream_t stream) {
  const float* x  = (const float*)d_in[0];
  const float* cb = (const float*)d_in[1];

  float* out      = (float*)d_out;
  float* out_xq   = out;                                  // [N,128]
  float* out_loss = out + (size_t)NTOK * D_;              // [1]
  float* out_idx  = out_loss + 1;                         // [N,4] (as float)
  float* out_s    = out_idx + (size_t)NTOK * NLVL;        // [N,4]

  double* lossacc = (double*)d_ws;                        // 4 doubles
  float*  en      = (float*)((char*)d_ws + 256);          // normalized codebooks (512 KB)

  hipMemsetAsync(d_ws, 0, 256, stream);
  normalize_cb<<<NLVL * NCODE, 64, 0, stream>>>(cb, en);
  rvq_main<<<NTOK / TOKB, TPB, 0, stream>>>(x, en, out_xq, out_idx, out_s, lossacc);
  finalize_loss<<<1, 1, 0, stream>>>(lossacc, out_loss);

  (void)in_sizes; (void)n_in; (void)out_size; (void)ws_size;
}